// Round 3
// baseline (547.789 us; speedup 1.0000x reference)
//
#include <hip/hip_runtime.h>

// lossFunc: masked BCE-with-logits + sum/cnt^2 scalar loss + two masked passthrough arrays.
// Memory-bound: 384 MiB read + 256 MiB write compulsory.

__global__ __launch_bounds__(256) void bce_main_kernel(
    const float* __restrict__ pred,
    const float* __restrict__ labels,
    const int*   __restrict__ scores,
    float* __restrict__ bp,            // d_out + 1            (binary_preds)
    float* __restrict__ gt,            // d_out + 1 + N        (ground_truths)
    double* __restrict__ ws_sum,
    unsigned long long* __restrict__ ws_cnt,
    int nq)                            // number of float4 quads
{
    double lsum = 0.0;
    unsigned int lcnt = 0;
    const int stride = gridDim.x * blockDim.x;

    for (int q = blockIdx.x * blockDim.x + threadIdx.x; q < nq; q += stride) {
        const float4 p = reinterpret_cast<const float4*>(pred)[q];
        const float4 y = reinterpret_cast<const float4*>(labels)[q];
        const int4   s = reinterpret_cast<const int4*>(scores)[q];
        const int base = q << 2;

        const float pv[4] = {p.x, p.y, p.z, p.w};
        const float yv[4] = {y.x, y.y, y.z, y.w};
        const int   sv[4] = {s.x, s.y, s.z, s.w};

        #pragma unroll
        for (int j = 0; j < 4; ++j) {
            const bool  m = (sv[j] == 1);
            const float x = pv[j];
            // masked passthrough outputs (scalar stores: arrays are only 4B-aligned)
            bp[base + j] = m ? x : 0.0f;
            gt[base + j] = m ? yv[j] : 0.0f;
            if (m) {
                // numerically stable BCE-with-logits: max(x,0) - x*y + log1p(exp(-|x|))
                const float bce = fmaxf(x, 0.0f) - x * yv[j] + log1pf(expf(-fabsf(x)));
                lsum += (double)bce;
                ++lcnt;
            }
        }
    }

    // wave (64-lane) butterfly reduction
    #pragma unroll
    for (int off = 32; off > 0; off >>= 1) {
        lsum += __shfl_down(lsum, off, 64);
        lcnt += __shfl_down(lcnt, off, 64);
    }

    __shared__ double       ssum[4];
    __shared__ unsigned int scnt[4];
    const int wid  = threadIdx.x >> 6;
    const int lane = threadIdx.x & 63;
    if (lane == 0) { ssum[wid] = lsum; scnt[wid] = lcnt; }
    __syncthreads();

    if (threadIdx.x == 0) {
        const double bs = ssum[0] + ssum[1] + ssum[2] + ssum[3];
        const unsigned long long bc =
            (unsigned long long)scnt[0] + scnt[1] + scnt[2] + scnt[3];
        atomicAdd(ws_sum, bs);
        atomicAdd(ws_cnt, bc);
    }
}

__global__ void bce_finalize_kernel(const double* __restrict__ ws_sum,
                                    const unsigned long long* __restrict__ ws_cnt,
                                    float* __restrict__ out)
{
    const double c = (double)(*ws_cnt);
    out[0] = (float)(*ws_sum / (c * c));
}

extern "C" void kernel_launch(void* const* d_in, const int* in_sizes, int n_in,
                              void* d_out, int out_size, void* d_ws, size_t ws_size,
                              hipStream_t stream) {
    const float* pred   = (const float*)d_in[0];
    const float* labels = (const float*)d_in[1];
    const int*   scores = (const int*)d_in[2];
    float* out = (float*)d_out;

    const int N  = in_sizes[0];       // 8192*4096 = 33,554,432 (divisible by 4)
    const int nq = N >> 2;

    double* ws_sum             = (double*)d_ws;
    unsigned long long* ws_cnt = (unsigned long long*)((char*)d_ws + 8);

    // ws is poisoned 0xAA before every timed launch — zero the accumulators.
    hipMemsetAsync(d_ws, 0, 16, stream);

    const int block = 256;
    const int grid  = 2048;           // 8 blocks/CU on 256 CUs, grid-stride

    bce_main_kernel<<<grid, block, 0, stream>>>(
        pred, labels, scores,
        out + 1,            // binary_preds
        out + 1 + N,        // ground_truths
        ws_sum, ws_cnt, nq);

    bce_finalize_kernel<<<1, 1, 0, stream>>>(ws_sum, ws_cnt, out);
}

// Round 6
// 525.341 us; speedup vs baseline: 1.0427x; 1.0427x over previous
//
#include <hip/hip_runtime.h>

// lossFunc: masked BCE-with-logits + sum/cnt^2 scalar loss + two masked passthrough arrays.
// Round 5: hardware transcendentals via AMDGCN builtins (round-4 __exp2f/__log2f
// hit host glibc decls). __builtin_amdgcn_exp2f = v_exp_f32 (2^x),
// __builtin_amdgcn_logf = v_log_f32 (log2 x).
// log1p(exp(-a)) = ln2*log2(1 + 2^(-a*log2e));  1+2^(-a') ∈ (1,2] so log2 is safe.

__global__ __launch_bounds__(256) void bce_main_kernel(
    const float* __restrict__ pred,
    const float* __restrict__ labels,
    const int*   __restrict__ scores,
    float* __restrict__ bp,            // d_out + 1            (binary_preds)
    float* __restrict__ gt,            // d_out + 1 + N        (ground_truths)
    double* __restrict__ ws_sum,
    unsigned long long* __restrict__ ws_cnt,
    int nq)                            // number of float4 quads
{
    const float LOG2E = 1.4426950408889634f;
    const float LN2   = 0.6931471805599453f;

    double lsum = 0.0;
    unsigned int lcnt = 0;
    const int stride = gridDim.x * blockDim.x;

    for (int q = blockIdx.x * blockDim.x + threadIdx.x; q < nq; q += stride) {
        const float4 p = reinterpret_cast<const float4*>(pred)[q];
        const float4 y = reinterpret_cast<const float4*>(labels)[q];
        const int4   s = reinterpret_cast<const int4*>(scores)[q];
        const int base = q << 2;

        const float pv[4] = {p.x, p.y, p.z, p.w};
        const float yv[4] = {y.x, y.y, y.z, y.w};
        const int   sv[4] = {s.x, s.y, s.z, s.w};

        float qsum = 0.0f;   // 4-element partial in f32; one f64 add per quad
        #pragma unroll
        for (int j = 0; j < 4; ++j) {
            const bool  m = (sv[j] == 1);
            const float x = pv[j];
            const float yy = yv[j];
            // masked passthrough outputs (scalar stores: arrays are only 4B-aligned)
            bp[base + j] = m ? x  : 0.0f;
            gt[base + j] = m ? yy : 0.0f;

            // stable BCE-with-logits via hardware exp2/log2:
            // max(x,0) - x*y + ln2*log2(1 + 2^(-|x|*log2e))
            const float a  = fabsf(x);
            const float u  = __builtin_amdgcn_exp2f(a * -LOG2E);   // v_exp_f32
            const float sp = __builtin_amdgcn_logf(1.0f + u) * LN2; // v_log_f32 + mul
            const float bce = fmaxf(x, 0.0f) - x * yy + sp;

            qsum += m ? bce : 0.0f;                      // branchless
            lcnt += (unsigned int)m;
        }
        lsum += (double)qsum;
    }

    // wave (64-lane) butterfly reduction
    #pragma unroll
    for (int off = 32; off > 0; off >>= 1) {
        lsum += __shfl_down(lsum, off, 64);
        lcnt += __shfl_down(lcnt, off, 64);
    }

    __shared__ double       ssum[4];
    __shared__ unsigned int scnt[4];
    const int wid  = threadIdx.x >> 6;
    const int lane = threadIdx.x & 63;
    if (lane == 0) { ssum[wid] = lsum; scnt[wid] = lcnt; }
    __syncthreads();

    if (threadIdx.x == 0) {
        const double bs = ssum[0] + ssum[1] + ssum[2] + ssum[3];
        const unsigned long long bc =
            (unsigned long long)scnt[0] + scnt[1] + scnt[2] + scnt[3];
        atomicAdd(ws_sum, bs);
        atomicAdd(ws_cnt, bc);
    }
}

__global__ void bce_finalize_kernel(const double* __restrict__ ws_sum,
                                    const unsigned long long* __restrict__ ws_cnt,
                                    float* __restrict__ out)
{
    const double c = (double)(*ws_cnt);
    out[0] = (float)(*ws_sum / (c * c));
}

extern "C" void kernel_launch(void* const* d_in, const int* in_sizes, int n_in,
                              void* d_out, int out_size, void* d_ws, size_t ws_size,
                              hipStream_t stream) {
    const float* pred   = (const float*)d_in[0];
    const float* labels = (const float*)d_in[1];
    const int*   scores = (const int*)d_in[2];
    float* out = (float*)d_out;

    const int N  = in_sizes[0];       // 8192*4096 = 33,554,432 (divisible by 4)
    const int nq = N >> 2;

    double* ws_sum             = (double*)d_ws;
    unsigned long long* ws_cnt = (unsigned long long*)((char*)d_ws + 8);

    // ws is poisoned 0xAA before every timed launch — zero the accumulators.
    (void)hipMemsetAsync(d_ws, 0, 16, stream);

    const int block = 256;
    const int grid  = 2048;           // 8 blocks/CU on 256 CUs, grid-stride

    bce_main_kernel<<<grid, block, 0, stream>>>(
        pred, labels, scores,
        out + 1,            // binary_preds
        out + 1 + N,        // ground_truths
        ws_sum, ws_cnt, nq);

    bce_finalize_kernel<<<1, 1, 0, stream>>>(ws_sum, ws_cnt, out);
}